// Round 1
// baseline (169.624 us; speedup 1.0000x reference)
//
#include <hip/hip_runtime.h>
#include <hip/hip_bf16.h>
#include <stdint.h>

// ===================================================================
// PriorLayer online BP scan, round 3. s_t = norm(diag(p_t) T s_{t-1}).
// R2 (54.7us/dispatch) was convoy-bound: 1 block/CU + 1 barrier/step
// => all 8 waves in lockstep phases (LDS burst -> MFMA chain -> VALU
// burst -> barrier), every pipe <=32% busy. Changes:
//  - CLEN 16 -> 8, NBLK 256 -> 512: TWO independent blocks per CU.
//    Two serial scan chains interleave per SIMD and fill each other's
//    latency/barrier gaps. (+43% step-slots, but pipes have headroom.)
//  - Burn-in steps gated: no sz/sl (8 v_log/lane!), no shuffles, no
//    pZL traffic during the 12 burn steps -- they are now just
//    MFMA + mul + cvt + state-write + barrier.
//  - MFMA accumulator split into 2 chains (dep depth 8 -> 4).
//  - Nontemporal out stores (streamed once; keep L2 for probs reuse).
// ===================================================================

#define DIM   256
#define SEQ   65536
#define G     16                    // chunks (MFMA columns) per block
#define CLEN  8                     // output steps per chunk
#define NBLK  (SEQ / (G * CLEN))    // 512 blocks -> 2 per CU
#define BURN  12
#define STEPS (BURN + CLEN)         // 20 (even — pairing relies on it)
#define NW    8
#define TPB   (NW * 64)
#define SROW  264                   // padded LDS row stride (bf16 elems)

typedef short bf16x8 __attribute__((ext_vector_type(8)));
typedef float f32x4  __attribute__((ext_vector_type(4)));
typedef float f32x2  __attribute__((ext_vector_type(2)));

static __device__ __forceinline__ unsigned short f2bf(float x) {
  __hip_bfloat16 h = __float2bfloat16(x);
  return *reinterpret_cast<unsigned short*>(&h);
}

// LDS-only barrier: do NOT drain vmcnt (global stores / prefetch loads
// stay in flight). lgkmcnt(0) orders all ds ops.
static __device__ __forceinline__ void lds_barrier() {
  asm volatile("s_waitcnt lgkmcnt(0)" ::: "memory");
  __builtin_amdgcn_s_barrier();
}

__global__ __launch_bounds__(TPB, 4)
void prior_scan_kernel(const float* __restrict__ probs,
                       const float* __restrict__ tp,
                       float* __restrict__ out) {
  // S_T: double-buffered transposed state [buf][chunk][row] (bf16).
  // pZL: double-buffered per-wave partials {sum u, sum u*ln u}.
  __shared__ __attribute__((aligned(16))) short S_T[2][G][SROW];
  __shared__ f32x2 pZL[2][NW][G];

  const int tid  = threadIdx.x;
  const int w    = tid >> 6;
  const int lane = tid & 63;
  const int n    = lane & 15;       // MFMA col = chunk within block
  const int quad = lane >> 4;
  const int cbase = blockIdx.x * G;
  const int r0 = (2 * w) * 16 + quad * 4;       // C/D row base, tile 0
  const int r1 = (2 * w + 1) * 16 + quad * 4;   // row-tile 1

  // ---- T into A-fragments: A[m=lane&15][k=quad*8+j]; row=(2w+rt)*16+m
  bf16x8 A[2][8];
#pragma unroll
  for (int rt = 0; rt < 2; rt++) {
    const int row = (2 * w + rt) * 16 + n;
#pragma unroll
    for (int kb = 0; kb < 8; kb++) {
      const float* p = tp + row * DIM + kb * 32 + quad * 8;
      f32x4 f0 = *reinterpret_cast<const f32x4*>(p);
      f32x4 f1 = *reinterpret_cast<const f32x4*>(p + 4);
      bf16x8 a;
#pragma unroll
      for (int j = 0; j < 4; j++) {
        a[j]     = (short)f2bf(f0[j]);
        a[4 + j] = (short)f2bf(f1[j]);
      }
      A[rt][kb] = a;
    }
  }

  // ---- init state buf 0 = uniform 1/256 (bf16-exact; scale-invariant)
  for (int i = tid; i < G * SROW; i += TPB)
    (&S_T[0][0][0])[i] = (short)0x3B80;

  // ---- observation fragment loader (lane-owned, direct from global)
  auto loadp = [&](int s, int rbase, bool clamp) -> f32x4 {
    int t = (cbase + n) * CLEN - BURN + s;
    if (clamp && t < 0) t = 0;      // value unused when t<0
    return *reinterpret_cast<const f32x4*>(probs + (size_t)t * DIM + rbase);
  };

  // 2-deep register prefetch ring
  f32x4 pf[2][2];
  pf[0][0] = loadp(0, r0, true); pf[0][1] = loadp(0, r1, true);
  pf[1][0] = loadp(1, r0, true); pf[1][1] = loadp(1, r1, true);

  lds_barrier();

  float qp[2][4];                   // q of previous step (deferred norm)

  // --- recurrence core: q = (T @ u) .* p   (2 split acc chains)
  auto matvec = [&](int cur, float q[2][4]) {
    f32x4 acc00 = {0.f,0.f,0.f,0.f}, acc01 = {0.f,0.f,0.f,0.f};
    f32x4 acc10 = {0.f,0.f,0.f,0.f}, acc11 = {0.f,0.f,0.f,0.f};
#pragma unroll
    for (int kb = 0; kb < 8; kb += 2) {
      bf16x8 b0 = *reinterpret_cast<const bf16x8*>(
          &S_T[cur][n][kb * 32 + quad * 8]);
      bf16x8 b1 = *reinterpret_cast<const bf16x8*>(
          &S_T[cur][n][(kb + 1) * 32 + quad * 8]);
      acc00 = __builtin_amdgcn_mfma_f32_16x16x32_bf16(A[0][kb],     b0, acc00, 0, 0, 0);
      acc10 = __builtin_amdgcn_mfma_f32_16x16x32_bf16(A[1][kb],     b0, acc10, 0, 0, 0);
      acc01 = __builtin_amdgcn_mfma_f32_16x16x32_bf16(A[0][kb + 1], b1, acc01, 0, 0, 0);
      acc11 = __builtin_amdgcn_mfma_f32_16x16x32_bf16(A[1][kb + 1], b1, acc11, 0, 0, 0);
    }
    f32x4 p0 = pf[cur][0], p1 = pf[cur][1];
#pragma unroll
    for (int v = 0; v < 4; v++) {
      q[0][v] = (acc00[v] + acc01[v]) * p0[v];  // C/D: row=quad*4+v, col=n
      q[1][v] = (acc10[v] + acc11[v]) * p1[v];
    }
  };

  auto write_state = [&](int nxt, const float q[2][4]) {
#pragma unroll
    for (int rt = 0; rt < 2; rt++) {
      ushort4 sp;
      sp.x = f2bf(q[rt][0] * 0.015625f);
      sp.y = f2bf(q[rt][1] * 0.015625f);
      sp.z = f2bf(q[rt][2] * 0.015625f);
      sp.w = f2bf(q[rt][3] * 0.015625f);
      *reinterpret_cast<ushort4*>(&S_T[nxt][n][rt ? r1 : r0]) = sp;
    }
  };

  // --- burn-in step: NO partials, NO finalize, NO qp carry
  auto burn_body = [&](int step, int cur, int nxt) {
    float q[2][4];
    matvec(cur, q);
    const int t = (cbase + n) * CLEN - BURN + step;
    if (t < 0) {                    // pre-start: hold uniform state
      ushort4 sp;
      sp.x = sp.y = sp.z = sp.w = (unsigned short)0x3B80;
      *reinterpret_cast<ushort4*>(&S_T[nxt][n][r0]) = sp;
      *reinterpret_cast<ushort4*>(&S_T[nxt][n][r1]) = sp;
    } else {
      write_state(nxt, q);
    }
    pf[cur][0] = loadp(step + 2, r0, true);   // step+2 <= BURN+1 < STEPS
    pf[cur][1] = loadp(step + 2, r1, true);
    lds_barrier();
  };

  // --- output step: partials + deferred finalize of step-1
  auto main_body = [&](int step, int cur, int nxt) {
    float q[2][4];
    matvec(cur, q);
    write_state(nxt, q);            // LDS write early (off VALU burst)

    float sz = 0.f, sl = 0.f;
#pragma unroll
    for (int rt = 0; rt < 2; rt++)
#pragma unroll
      for (int v = 0; v < 4; v++) {
        float qq = q[rt][v];
        sz += qq;
        sl += qq * __logf(qq + 1e-30f);
      }
    sz += __shfl_xor(sz, 16); sz += __shfl_xor(sz, 32);
    sl += __shfl_xor(sl, 16); sl += __shfl_xor(sl, 32);
    if (lane < 16) pZL[cur][w][n] = f32x2{sz, sl};

    if (step > BURN) {              // deferred finalize of step-1
      float Z = 0.f, L = 0.f;
#pragma unroll
      for (int ww = 0; ww < NW; ww++) {
        f32x2 v = pZL[nxt][ww][n];  // nxt == (step-1)&1
        Z += v[0]; L += v[1];
      }
      const float zi = __builtin_amdgcn_rcpf(Z);
      const int t1 = (cbase + n) * CLEN + (step - 1 - BURN);
#pragma unroll
      for (int rt = 0; rt < 2; rt++) {
        f32x4 o;
#pragma unroll
        for (int v = 0; v < 4; v++) o[v] = qp[rt][v] * zi;
        __builtin_nontemporal_store(
            o, reinterpret_cast<f32x4*>(out + (size_t)t1 * DIM + (rt ? r1 : r0)));
      }
      if (tid < 16)                 // n == tid for these lanes
        __builtin_nontemporal_store(__logf(Z) - L * zi,
                                    out + (size_t)SEQ * DIM + t1);
    }

#pragma unroll
    for (int rt = 0; rt < 2; rt++)
#pragma unroll
      for (int v = 0; v < 4; v++) qp[rt][v] = q[rt][v];
    int ps = step + 2; if (ps > STEPS - 1) ps = STEPS - 1;
    pf[cur][0] = loadp(ps, r0, false);
    pf[cur][1] = loadp(ps, r1, false);
    lds_barrier();
  };

  for (int s = 0; s < BURN; s += 2) {        // BURN even
    burn_body(s, 0, 1);
    burn_body(s + 1, 1, 0);
  }
  for (int s = BURN; s < STEPS; s += 2) {    // STEPS even
    main_body(s, 0, 1);
    main_body(s + 1, 1, 0);
  }

  // --- tail: finalize last step (its partials sit in pZL[(STEPS-1)&1]=pZL[1])
  {
    float Z = 0.f, L = 0.f;
#pragma unroll
    for (int ww = 0; ww < NW; ww++) {
      f32x2 v = pZL[1][ww][n];
      Z += v[0]; L += v[1];
    }
    const float zi = __builtin_amdgcn_rcpf(Z);
    const int t1 = (cbase + n) * CLEN + (CLEN - 1);
#pragma unroll
    for (int rt = 0; rt < 2; rt++) {
      f32x4 o;
#pragma unroll
      for (int v = 0; v < 4; v++) o[v] = qp[rt][v] * zi;
      __builtin_nontemporal_store(
          o, reinterpret_cast<f32x4*>(out + (size_t)t1 * DIM + (rt ? r1 : r0)));
    }
    if (tid < 16)
      __builtin_nontemporal_store(__logf(Z) - L * zi,
                                  out + (size_t)SEQ * DIM + t1);
  }
}

extern "C" void kernel_launch(void* const* d_in, const int* in_sizes, int n_in,
                              void* d_out, int out_size, void* d_ws, size_t ws_size,
                              hipStream_t stream) {
  const float* probs = (const float*)d_in[0];   // (65536, 256)
  const float* tp    = (const float*)d_in[1];   // (256, 256)
  float* out         = (float*)d_out;           // 65536*256 probs + 65536 H

  hipLaunchKernelGGL(prior_scan_kernel, dim3(NBLK), dim3(TPB), 0, stream,
                     probs, tp, out);
}

// Round 2
// 144.435 us; speedup vs baseline: 1.1744x; 1.1744x over previous
//
#include <hip/hip_runtime.h>
#include <hip/hip_bf16.h>
#include <stdint.h>

// ===================================================================
// PriorLayer online BP scan, round 4. s_t = norm(diag(p_t) T s_{t-1}).
// R3 falsified "add waves to overlap": 2 blocks/CU gave ZERO overlap
// (+12% per step-block) and halving VALU gave zero. Invariant across
// R1-R3 (~4700 cyc/step): 8-wave barrier-locked all-to-all => aligned
// 64x ds_read_b128 bursts + bpermute round-trips + 8-way resync.
// Burst queueing latency is the floor, not pipe throughput. Changes:
//  - 4 waves x 4 row-tiles (A frags 128 VGPR, 1 wave/SIMD): LDS burst
//    halves (32 reads/step), barrier group halves.
//  - NO cross-lane shuffles in the chain: each lane's 16 q-values are
//    one (wave,quad) row-group => lane-private {sum q, sum q ln q}
//    partial written straight to pZL[16][16]; deferred finalize sums
//    16 partials (broadcast reads, off the serial chain).
//  - Revert to CLEN=16, NBLK=256, 1 block/CU (best steps/output).
//  - Keep: burn gating, split MFMA chains, nontemporal out stores,
//    one lgkmcnt-only barrier per step, 2-deep prefetch ring.
// ===================================================================

#define DIM   256
#define SEQ   65536
#define G     16                    // chunks (MFMA columns) per block
#define CLEN  16                    // output steps per chunk
#define NBLK  (SEQ / (G * CLEN))    // 256 blocks -> 1 per CU
#define BURN  12
#define STEPS (BURN + CLEN)         // 28 (even — pairing relies on it)
#define NW    4
#define TPB   (NW * 64)             // 256
#define SROW  264                   // padded LDS row stride (bf16 elems)

typedef short bf16x8 __attribute__((ext_vector_type(8)));
typedef float f32x4  __attribute__((ext_vector_type(4)));
typedef float f32x2  __attribute__((ext_vector_type(2)));

static __device__ __forceinline__ unsigned short f2bf(float x) {
  __hip_bfloat16 h = __float2bfloat16(x);
  return *reinterpret_cast<unsigned short*>(&h);
}

// LDS-only barrier: do NOT drain vmcnt (global stores / prefetch loads
// stay in flight). lgkmcnt(0) orders all ds ops.
static __device__ __forceinline__ void lds_barrier() {
  asm volatile("s_waitcnt lgkmcnt(0)" ::: "memory");
  __builtin_amdgcn_s_barrier();
}

__global__ __launch_bounds__(TPB, 1)
void prior_scan_kernel(const float* __restrict__ probs,
                       const float* __restrict__ tp,
                       float* __restrict__ out) {
  // S_T: double-buffered transposed state [buf][chunk][row] (bf16).
  // pZL: double-buffered lane partials [buf][w*4+quad][chunk].
  __shared__ __attribute__((aligned(16))) short S_T[2][G][SROW];
  __shared__ __attribute__((aligned(16))) f32x2 pZL[2][16][G];

  const int tid  = threadIdx.x;
  const int w    = tid >> 6;
  const int lane = tid & 63;
  const int n    = lane & 15;       // MFMA col = chunk within block
  const int quad = lane >> 4;
  const int cbase = blockIdx.x * G;
  const int wq = w * 4 + quad;

  int rb[4];                        // C/D row bases, 4 row-tiles
#pragma unroll
  for (int rt = 0; rt < 4; rt++) rb[rt] = (w * 4 + rt) * 16 + quad * 4;

  // ---- T into A-fragments: A[m=lane&15][k=quad*8+j]; row=(4w+rt)*16+m
  bf16x8 A[4][8];
#pragma unroll
  for (int rt = 0; rt < 4; rt++) {
    const int row = (w * 4 + rt) * 16 + n;
#pragma unroll
    for (int kb = 0; kb < 8; kb++) {
      const float* p = tp + row * DIM + kb * 32 + quad * 8;
      f32x4 f0 = *reinterpret_cast<const f32x4*>(p);
      f32x4 f1 = *reinterpret_cast<const f32x4*>(p + 4);
      bf16x8 a;
#pragma unroll
      for (int j = 0; j < 4; j++) {
        a[j]     = (short)f2bf(f0[j]);
        a[4 + j] = (short)f2bf(f1[j]);
      }
      A[rt][kb] = a;
    }
  }

  // ---- init state buf 0 = uniform 1/256 (bf16-exact; scale-invariant)
  for (int i = tid; i < G * SROW; i += TPB)
    (&S_T[0][0][0])[i] = (short)0x3B80;

  // ---- observation fragment loader (lane-owned, direct from global)
  auto loadp = [&](int s, int rbase, bool clamp) -> f32x4 {
    int t = (cbase + n) * CLEN - BURN + s;
    if (clamp && t < 0) t = 0;      // value unused when t<0
    return *reinterpret_cast<const f32x4*>(probs + (size_t)t * DIM + rbase);
  };

  // 2-deep register prefetch ring (4 row-tiles per slot)
  f32x4 pf[2][4];
#pragma unroll
  for (int rt = 0; rt < 4; rt++) {
    pf[0][rt] = loadp(0, rb[rt], true);
    pf[1][rt] = loadp(1, rb[rt], true);
  }

  lds_barrier();

  float qp[4][4];                   // q of previous step (deferred norm)

  // --- recurrence core: q = (T @ u) .* p   (even/odd-kb split chains)
  auto matvec = [&](int cur, float q[4][4]) {
    f32x4 accE[4], accO[4];
#pragma unroll
    for (int rt = 0; rt < 4; rt++) {
      accE[rt] = f32x4{0.f, 0.f, 0.f, 0.f};
      accO[rt] = f32x4{0.f, 0.f, 0.f, 0.f};
    }
#pragma unroll
    for (int kb = 0; kb < 8; kb += 2) {
      bf16x8 b0 = *reinterpret_cast<const bf16x8*>(
          &S_T[cur][n][kb * 32 + quad * 8]);
      bf16x8 b1 = *reinterpret_cast<const bf16x8*>(
          &S_T[cur][n][(kb + 1) * 32 + quad * 8]);
#pragma unroll
      for (int rt = 0; rt < 4; rt++) {
        accE[rt] = __builtin_amdgcn_mfma_f32_16x16x32_bf16(A[rt][kb],     b0, accE[rt], 0, 0, 0);
        accO[rt] = __builtin_amdgcn_mfma_f32_16x16x32_bf16(A[rt][kb + 1], b1, accO[rt], 0, 0, 0);
      }
    }
#pragma unroll
    for (int rt = 0; rt < 4; rt++) {
      f32x4 p = pf[cur][rt];
#pragma unroll
      for (int v = 0; v < 4; v++)
        q[rt][v] = (accE[rt][v] + accO[rt][v]) * p[v];  // row=quad*4+v, col=n
    }
  };

  auto write_state = [&](int nxt, const float q[4][4]) {
#pragma unroll
    for (int rt = 0; rt < 4; rt++) {
      ushort4 sp;
      sp.x = f2bf(q[rt][0] * 0.015625f);
      sp.y = f2bf(q[rt][1] * 0.015625f);
      sp.z = f2bf(q[rt][2] * 0.015625f);
      sp.w = f2bf(q[rt][3] * 0.015625f);
      *reinterpret_cast<ushort4*>(&S_T[nxt][n][rb[rt]]) = sp;
    }
  };

  // --- burn-in step: NO partials, NO finalize, NO qp carry
  auto burn_body = [&](int step, int cur, int nxt) {
    float q[4][4];
    matvec(cur, q);
    const int t = (cbase + n) * CLEN - BURN + step;
    if (t < 0) {                    // pre-start: hold uniform state
      ushort4 sp;
      sp.x = sp.y = sp.z = sp.w = (unsigned short)0x3B80;
#pragma unroll
      for (int rt = 0; rt < 4; rt++)
        *reinterpret_cast<ushort4*>(&S_T[nxt][n][rb[rt]]) = sp;
    } else {
      write_state(nxt, q);
    }
#pragma unroll
    for (int rt = 0; rt < 4; rt++)
      pf[cur][rt] = loadp(step + 2, rb[rt], true);  // step+2 <= BURN+1
    lds_barrier();
  };

  // --- output step: lane-private partials + deferred finalize of step-1
  auto main_body = [&](int step, int cur, int nxt) {
    float q[4][4];
    matvec(cur, q);
    write_state(nxt, q);            // LDS write early

    // lane-private partial over this lane's 16 rows (no cross-lane ops!)
    float sz0 = 0.f, sl0 = 0.f, sz1 = 0.f, sl1 = 0.f;
#pragma unroll
    for (int rt = 0; rt < 2; rt++)
#pragma unroll
      for (int v = 0; v < 4; v++) {
        float qq = q[rt][v];
        sz0 += qq;
        sl0 += qq * __logf(qq + 1e-30f);
      }
#pragma unroll
    for (int rt = 2; rt < 4; rt++)
#pragma unroll
      for (int v = 0; v < 4; v++) {
        float qq = q[rt][v];
        sz1 += qq;
        sl1 += qq * __logf(qq + 1e-30f);
      }
    pZL[cur][wq][n] = f32x2{sz0 + sz1, sl0 + sl1};

    if (step > BURN) {              // deferred finalize of step-1
      float Z = 0.f, L = 0.f;
#pragma unroll
      for (int ww = 0; ww < 16; ww++) {
        f32x2 v = pZL[nxt][ww][n];  // nxt == (step-1)&1
        Z += v[0]; L += v[1];
      }
      const float zi = __builtin_amdgcn_rcpf(Z);
      const int t1 = (cbase + n) * CLEN + (step - 1 - BURN);
#pragma unroll
      for (int rt = 0; rt < 4; rt++) {
        f32x4 o;
#pragma unroll
        for (int v = 0; v < 4; v++) o[v] = qp[rt][v] * zi;
        __builtin_nontemporal_store(
            o, reinterpret_cast<f32x4*>(out + (size_t)t1 * DIM + rb[rt]));
      }
      if (tid < 16)                 // n == tid for these lanes
        __builtin_nontemporal_store(__logf(Z) - L * zi,
                                    out + (size_t)SEQ * DIM + t1);
    }

#pragma unroll
    for (int rt = 0; rt < 4; rt++)
#pragma unroll
      for (int v = 0; v < 4; v++) qp[rt][v] = q[rt][v];
    int ps = step + 2; if (ps > STEPS - 1) ps = STEPS - 1;
#pragma unroll
    for (int rt = 0; rt < 4; rt++)
      pf[cur][rt] = loadp(ps, rb[rt], false);
    lds_barrier();
  };

  for (int s = 0; s < BURN; s += 2) {        // BURN even
    burn_body(s, 0, 1);
    burn_body(s + 1, 1, 0);
  }
  for (int s = BURN; s < STEPS; s += 2) {    // STEPS even
    main_body(s, 0, 1);
    main_body(s + 1, 1, 0);
  }

  // --- tail: finalize last step (partials in pZL[(STEPS-1)&1] = pZL[1])
  {
    float Z = 0.f, L = 0.f;
#pragma unroll
    for (int ww = 0; ww < 16; ww++) {
      f32x2 v = pZL[1][ww][n];
      Z += v[0]; L += v[1];
    }
    const float zi = __builtin_amdgcn_rcpf(Z);
    const int t1 = (cbase + n) * CLEN + (CLEN - 1);
#pragma unroll
    for (int rt = 0; rt < 4; rt++) {
      f32x4 o;
#pragma unroll
      for (int v = 0; v < 4; v++) o[v] = qp[rt][v] * zi;
      __builtin_nontemporal_store(
          o, reinterpret_cast<f32x4*>(out + (size_t)t1 * DIM + rb[rt]));
    }
    if (tid < 16)
      __builtin_nontemporal_store(__logf(Z) - L * zi,
                                  out + (size_t)SEQ * DIM + t1);
  }
}

extern "C" void kernel_launch(void* const* d_in, const int* in_sizes, int n_in,
                              void* d_out, int out_size, void* d_ws, size_t ws_size,
                              hipStream_t stream) {
  const float* probs = (const float*)d_in[0];   // (65536, 256)
  const float* tp    = (const float*)d_in[1];   // (256, 256)
  float* out         = (float*)d_out;           // 65536*256 probs + 65536 H

  hipLaunchKernelGGL(prior_scan_kernel, dim3(NBLK), dim3(TPB), 0, stream,
                     probs, tp, out);
}